// Round 1
// baseline (1329.020 us; speedup 1.0000x reference)
//
#include <hip/hip_runtime.h>

// ---------- types ----------
typedef __attribute__((ext_vector_type(8))) __bf16 bf16x8;
typedef __attribute__((ext_vector_type(4))) float f32x4;

__device__ __forceinline__ unsigned short f2b(float f) {
    union { float f; unsigned u; } v; v.f = f;
    unsigned r = v.u + 0x7FFFu + ((v.u >> 16) & 1u);   // RNE
    return (unsigned short)(r >> 16);
}

// ---------- conversion kernels ----------
// x f32 -> bf16, 4 elems/thread
__global__ __launch_bounds__(256) void conv_x_kernel(const float* __restrict__ in,
                                                     unsigned short* __restrict__ out,
                                                     long n4) {
    long i = (long)blockIdx.x * 256 + threadIdx.x;
    if (i >= n4) return;
    const float4 v = ((const float4*)in)[i];
    ushort4 o;
    o.x = f2b(v.x); o.y = f2b(v.y); o.z = f2b(v.z); o.w = f2b(v.w);
    ((ushort4*)out)[i] = o;
}

// W [K][N] f32 -> Wt [N][K] bf16 (coalesced read, scattered 2B write; small)
__global__ __launch_bounds__(256) void convw_kernel(const float* __restrict__ W,
                                                    unsigned short* __restrict__ Wt,
                                                    int K, int N) {
    int t = blockIdx.x * 256 + threadIdx.x;
    if (t >= K * N) return;
    int k = t / N, n = t - k * N;
    Wt[(size_t)n * K + k] = f2b(W[t]);
}

// ---------- scatter: agg[dst] += y[src], HID=512, 2 edges/block ----------
__global__ __launch_bounds__(256) void scatter_kernel(const float* __restrict__ y,
                                                      const int* __restrict__ src,
                                                      const int* __restrict__ dst,
                                                      float* __restrict__ agg) {
    int e = blockIdx.x * 2 + (threadIdx.x >> 7);
    int c = (threadIdx.x & 127) << 2;
    int s = src[e], d = dst[e];
    const float4 v = *(const float4*)(y + (size_t)s * 512 + c);
    float* p = agg + (size_t)d * 512 + c;
    atomicAdd(p + 0, v.x); atomicAdd(p + 1, v.y);
    atomicAdd(p + 2, v.z); atomicAdd(p + 3, v.w);
}

// ---------- h1 = bf16(relu(y + agg + b1)) ----------
__global__ __launch_bounds__(256) void h1_kernel(const float* __restrict__ y,
                                                 const float* __restrict__ agg,
                                                 const float* __restrict__ b1,
                                                 unsigned short* __restrict__ out) {
    size_t i = (size_t)blockIdx.x * 256 + threadIdx.x;
    size_t i4 = i * 4;
    int c = (int)(i4 & 511);
    float4 a = ((const float4*)y)[i];
    float4 g = ((const float4*)agg)[i];
    float4 b = *(const float4*)(b1 + c);
    ushort4 o;
    o.x = f2b(fmaxf(a.x + g.x + b.x, 0.f));
    o.y = f2b(fmaxf(a.y + g.y + b.y, 0.f));
    o.z = f2b(fmaxf(a.z + g.z + b.z, 0.f));
    o.w = f2b(fmaxf(a.w + g.w + b.w, 0.f));
    ((ushort4*)out)[i] = o;
}

// ---------- MFMA GEMM: C[M][512] = A[M][K](bf16) @ Bt[512][K](bf16)^T ----------
// EPI 0: Cf = acc                      (y = x@W1, no bias)
// EPI 1: Cf = acc+bias; Cb = bf16(Cf)  (h = h1@W2+b2, dual store)
// EPI 2: alpha[row] += sum_col tanh(acc+bias)*Wa[col]   (gating, fused)
template <int KDIM, int EPI>
__global__ __launch_bounds__(256) void gemm_bt(const unsigned short* __restrict__ A,
                                               const unsigned short* __restrict__ Bt,
                                               const float* __restrict__ bias,
                                               float* __restrict__ Cf,
                                               unsigned short* __restrict__ Cb,
                                               const float* __restrict__ Wa,
                                               float* __restrict__ alphaOut,
                                               int M) {
    constexpr int BM = 128, BN = 128, BK = 32;
    __shared__ __align__(16) unsigned short As[BM * BK];  // 8 KB, row-major [row][K=32]
    __shared__ __align__(16) unsigned short Bs[BN * BK];  // 8 KB

    const int tid = threadIdx.x;
    const int lane = tid & 63;
    const int wv = tid >> 6;          // 4 waves, 2x2
    const int wm = wv >> 1, wn = wv & 1;
    const long row0 = (long)blockIdx.x * BM;
    const int col0 = blockIdx.y * BN;

    f32x4 acc[4][4];
#pragma unroll
    for (int m = 0; m < 4; m++)
#pragma unroll
        for (int n = 0; n < 4; n++)
#pragma unroll
            for (int r = 0; r < 4; r++) acc[m][n][r] = 0.f;

    const int sr = tid >> 2;      // staging row within 64-row chunk
    const int sk = tid & 3;       // which 16B piece of the 64B row
    const char* Ab = (const char*)A;
    const char* Bb = (const char*)Bt;
    const unsigned long stride = (unsigned long)KDIM * 2;

    for (int k0 = 0; k0 < KDIM; k0 += BK) {
        __syncthreads();  // previous iter's LDS reads complete
#pragma unroll
        for (int c = 0; c < 2; c++) {
            long ar = row0 + c * 64 + sr;
            if (ar > M - 1) ar = M - 1;                 // clamp tail reads
            const void* ga = Ab + (unsigned long)ar * stride + (unsigned long)k0 * 2 + sk * 16;
            __builtin_amdgcn_global_load_lds(
                (const __attribute__((address_space(1))) void*)ga,
                (__attribute__((address_space(3))) void*)((char*)As + c * 4096 + wv * 1024),
                16, 0, 0);
            long br = col0 + c * 64 + sr;               // always < 512
            const void* gb = Bb + (unsigned long)br * stride + (unsigned long)k0 * 2 + sk * 16;
            __builtin_amdgcn_global_load_lds(
                (const __attribute__((address_space(1))) void*)gb,
                (__attribute__((address_space(3))) void*)((char*)Bs + c * 4096 + wv * 1024),
                16, 0, 0);
        }
        __syncthreads();  // drains vmcnt(0): LDS filled

        const int kb = (lane >> 4) * 16;   // byte offset of this lane's 8xK chunk
        const int fr = lane & 15;
        bf16x8 af[4], bfr[4];
#pragma unroll
        for (int m = 0; m < 4; m++)
            af[m] = *(const bf16x8*)((const char*)As + (wm * 64 + m * 16 + fr) * 64 + kb);
#pragma unroll
        for (int n = 0; n < 4; n++)
            bfr[n] = *(const bf16x8*)((const char*)Bs + (wn * 64 + n * 16 + fr) * 64 + kb);
#pragma unroll
        for (int m = 0; m < 4; m++)
#pragma unroll
            for (int n = 0; n < 4; n++)
                acc[m][n] = __builtin_amdgcn_mfma_f32_16x16x32_bf16(af[m], bfr[n], acc[m][n], 0, 0, 0);
    }

    // epilogue: D row = (lane>>4)*4 + r, col = lane&15  [m89-verified]
    if constexpr (EPI != 2) {
#pragma unroll
        for (int m = 0; m < 4; m++)
#pragma unroll
            for (int r = 0; r < 4; r++) {
                long grow = row0 + wm * 64 + m * 16 + ((lane >> 4) << 2) + r;
                if (grow < M) {
#pragma unroll
                    for (int n = 0; n < 4; n++) {
                        int col = col0 + wn * 64 + n * 16 + (lane & 15);
                        float v = acc[m][n][r];
                        if constexpr (EPI == 1) v += bias[col];
                        Cf[(size_t)grow * 512 + col] = v;
                        if constexpr (EPI == 1) Cb[(size_t)grow * 512 + col] = f2b(v);
                    }
                }
            }
    } else {
        float part[4][4];
#pragma unroll
        for (int m = 0; m < 4; m++)
#pragma unroll
            for (int r = 0; r < 4; r++) part[m][r] = 0.f;
#pragma unroll
        for (int n = 0; n < 4; n++) {
            int col = col0 + wn * 64 + n * 16 + (lane & 15);
            float w = Wa[col];
            float bb = bias[col];
#pragma unroll
            for (int m = 0; m < 4; m++)
#pragma unroll
                for (int r = 0; r < 4; r++)
                    part[m][r] += tanhf(acc[m][n][r] + bb) * w;
        }
#pragma unroll
        for (int m = 0; m < 4; m++)
#pragma unroll
            for (int r = 0; r < 4; r++) {
                float s = part[m][r];
#pragma unroll
                for (int o = 1; o < 16; o <<= 1) s += __shfl_xor(s, o, 64);
                if ((lane & 15) == 0) {
                    long grow = row0 + wm * 64 + m * 16 + ((lane >> 4) << 2) + r;
                    if (grow < M) atomicAdd(&alphaOut[grow], s);
                }
            }
    }
}

// ---------- softmax over 20000 scalars (ba cancels in softmax) ----------
__global__ __launch_bounds__(1024) void softmax_kernel(const float* __restrict__ alpha,
                                                       float* __restrict__ att, int N) {
    __shared__ float red[16];
    __shared__ float bc[2];
    int tid = threadIdx.x, lane = tid & 63, wv = tid >> 6;
    float m = -3.4e38f;
    for (int i = tid; i < N; i += 1024) m = fmaxf(m, alpha[i]);
#pragma unroll
    for (int o = 32; o > 0; o >>= 1) m = fmaxf(m, __shfl_xor(m, o, 64));
    if (lane == 0) red[wv] = m;
    __syncthreads();
    if (tid == 0) {
        float mm = red[0];
        for (int i = 1; i < 16; i++) mm = fmaxf(mm, red[i]);
        bc[0] = mm;
    }
    __syncthreads();
    float Mx = bc[0];
    float s = 0.f;
    for (int i = tid; i < N; i += 1024) s += expf(alpha[i] - Mx);
#pragma unroll
    for (int o = 32; o > 0; o >>= 1) s += __shfl_xor(s, o, 64);
    if (lane == 0) red[wv] = s;
    __syncthreads();
    if (tid == 0) {
        float ss = 0.f;
        for (int i = 0; i < 16; i++) ss += red[i];
        bc[1] = ss;
    }
    __syncthreads();
    float inv = 1.f / bc[1];
    for (int i = tid; i < N; i += 1024) att[i] = expf(alpha[i] - Mx) * inv;
}

// ---------- launch ----------
extern "C" void kernel_launch(void* const* d_in, const int* in_sizes, int n_in,
                              void* d_out, int out_size, void* d_ws, size_t ws_size,
                              hipStream_t stream) {
    const float* x  = (const float*)d_in[0];
    const int*   ei = (const int*)d_in[1];     // [2][160000]: src then dst
    const float* W1 = (const float*)d_in[2];
    const float* b1 = (const float*)d_in[3];
    const float* W2 = (const float*)d_in[4];
    const float* b2 = (const float*)d_in[5];
    const float* Wg = (const float*)d_in[6];
    const float* bg = (const float*)d_in[7];
    const float* Wa = (const float*)d_in[8];
    // d_in[9] = ba: cancels in softmax, unused.

    const int M = 20000, IN = 2048, H = 512, E = 160000;

    char* ws = (char*)d_ws;
    // layout (bytes). x_b is dead after GEMM1; agg aliases it (stream-ordered).
    unsigned short* x_b  = (unsigned short*)ws;                    //  81,920,000
    float*          agg  = (float*)ws;                             //  40,960,000 (alias)
    float*          y    = (float*)(ws + 81920000);                //  40,960,000
    unsigned short* W1t  = (unsigned short*)(ws + 122880000);      //   2,097,152
    unsigned short* W2t  = (unsigned short*)(ws + 124977152);      //     524,288
    unsigned short* Wgt  = (unsigned short*)(ws + 125501440);      //     524,288
    unsigned short* h1b  = (unsigned short*)(ws + 126025728);      //  20,480,000
    unsigned short* hb   = (unsigned short*)(ws + 146505728);      //  20,480,000
    float*          alpha= (float*)(ws + 166985728);               //      80,000

    float* hout = (float*)d_out;                 // [20000][512] f32
    float* att  = hout + (size_t)M * H;          // [20000] f32

    // 1) conversions
    conv_x_kernel<<<40000, 256, 0, stream>>>(x, x_b, (long)M * IN / 4);
    convw_kernel<<<4096, 256, 0, stream>>>(W1, W1t, IN, H);
    convw_kernel<<<1024, 256, 0, stream>>>(W2, W2t, H, H);
    convw_kernel<<<1024, 256, 0, stream>>>(Wg, Wgt, H, H);

    // 2) y = x @ W1   (42 GFLOP, bf16 MFMA)
    gemm_bt<2048, 0><<<dim3(157, 4), 256, 0, stream>>>(x_b, W1t, nullptr, y, nullptr, nullptr, nullptr, M);

    // 3) agg = segment_sum(y[src], dst)  (linearity: scatter in HID domain)
    hipMemsetAsync(agg, 0, (size_t)M * H * 4, stream);
    scatter_kernel<<<E / 2, 256, 0, stream>>>(y, ei, ei + E, agg);

    // 4) h1 = bf16(relu(y + agg + b1))
    h1_kernel<<<10000, 256, 0, stream>>>(y, agg, b1, h1b);

    // 5) h = h1 @ W2 + b2  (f32 -> d_out, bf16 copy -> hb)
    gemm_bt<512, 1><<<dim3(157, 4), 256, 0, stream>>>(h1b, W2t, b2, hout, hb, nullptr, nullptr, M);

    // 6) alpha = rowsum(tanh(h @ Wg + bg) * Wa)   (fused epilogue)
    hipMemsetAsync(alpha, 0, (size_t)M * 4, stream);
    gemm_bt<512, 2><<<dim3(157, 4), 256, 0, stream>>>(hb, Wgt, bg, nullptr, nullptr, Wa, alpha, M);

    // 7) att = softmax(alpha)
    softmax_kernel<<<1, 1024, 0, stream>>>(alpha, att, M);
}

// Round 2
// 346.359 us; speedup vs baseline: 3.8371x; 3.8371x over previous
//
#include <hip/hip_runtime.h>

// ---------- types ----------
typedef __attribute__((ext_vector_type(8))) __bf16 bf16x8;
typedef __attribute__((ext_vector_type(4))) float f32x4;

__device__ __forceinline__ unsigned short f2b(float f) {
    union { float f; unsigned u; } v; v.f = f;
    unsigned r = v.u + 0x7FFFu + ((v.u >> 16) & 1u);   // RNE
    return (unsigned short)(r >> 16);
}

// ---------- conversion kernels ----------
__global__ __launch_bounds__(256) void conv_x_kernel(const float* __restrict__ in,
                                                     unsigned short* __restrict__ out,
                                                     long n4) {
    long i = (long)blockIdx.x * 256 + threadIdx.x;
    if (i >= n4) return;
    const float4 v = ((const float4*)in)[i];
    ushort4 o;
    o.x = f2b(v.x); o.y = f2b(v.y); o.z = f2b(v.z); o.w = f2b(v.w);
    ((ushort4*)out)[i] = o;
}

__global__ __launch_bounds__(256) void convw_kernel(const float* __restrict__ W,
                                                    unsigned short* __restrict__ Wt,
                                                    int K, int N) {
    int t = blockIdx.x * 256 + threadIdx.x;
    if (t >= K * N) return;
    int k = t / N, n = t - k * N;
    Wt[(size_t)n * K + k] = f2b(W[t]);
}

// ---------- CSR build (by dst) ----------
__global__ __launch_bounds__(256) void count_kernel(const int* __restrict__ dst,
                                                    int* __restrict__ counts, int E) {
    int e = blockIdx.x * 256 + threadIdx.x;
    if (e < E) atomicAdd(&counts[dst[e]], 1);
}

// exclusive scan of counts[0..N) -> offs[0..N], single block of 1024
__global__ __launch_bounds__(1024) void scan_kernel(const int* __restrict__ counts,
                                                    int* __restrict__ offs, int N) {
    __shared__ int wsum[16], wpre[16];
    const int CH = 20;                       // 1024*20 >= 20000
    int tid = threadIdx.x, lane = tid & 63, wv = tid >> 6;
    int base = tid * CH;
    int s = 0;
    for (int i = 0; i < CH; i++) { int idx = base + i; s += (idx < N) ? counts[idx] : 0; }
    int run = s;
#pragma unroll
    for (int o = 1; o < 64; o <<= 1) { int v = __shfl_up(run, o, 64); if (lane >= o) run += v; }
    if (lane == 63) wsum[wv] = run;
    __syncthreads();
    if (tid == 0) { int acc = 0; for (int w = 0; w < 16; w++) { wpre[w] = acc; acc += wsum[w]; } }
    __syncthreads();
    int pre = wpre[wv] + (run - s);          // exclusive prefix of this thread's chunk
    for (int i = 0; i < CH; i++) {
        int idx = base + i;
        if (idx <= N) offs[idx] = pre;
        pre += (idx < N) ? counts[idx] : 0;
    }
}

__global__ __launch_bounds__(256) void bucket_kernel(const int* __restrict__ src,
                                                     const int* __restrict__ dst,
                                                     const int* __restrict__ offs,
                                                     int* __restrict__ cursor,
                                                     int* __restrict__ eids, int E) {
    int e = blockIdx.x * 256 + threadIdx.x;
    if (e >= E) return;
    int d = dst[e];
    int pos = atomicAdd(&cursor[d], 1);
    eids[offs[d] + pos] = src[e];
}

// ---------- gather + h1 fused: h1 = bf16(relu(y[i] + sum_j y[eids] + b1)) ----------
__global__ __launch_bounds__(256) void gather_h1_kernel(const float* __restrict__ y,
                                                        const int* __restrict__ offs,
                                                        const int* __restrict__ eids,
                                                        const float* __restrict__ b1,
                                                        unsigned short* __restrict__ h1b,
                                                        int N) {
    int node = blockIdx.x * 2 + (threadIdx.x >> 7);
    if (node >= N) return;
    int c = (threadIdx.x & 127) << 2;
    float4 s = *(const float4*)(y + (size_t)node * 512 + c);   // self term (eps=0)
    int beg = offs[node], end = offs[node + 1];
    for (int k = beg; k < end; k++) {
        int sn = eids[k];
        const float4 v = *(const float4*)(y + (size_t)sn * 512 + c);
        s.x += v.x; s.y += v.y; s.z += v.z; s.w += v.w;
    }
    const float4 b = *(const float4*)(b1 + c);
    ushort4 o;
    o.x = f2b(fmaxf(s.x + b.x, 0.f));
    o.y = f2b(fmaxf(s.y + b.y, 0.f));
    o.z = f2b(fmaxf(s.z + b.z, 0.f));
    o.w = f2b(fmaxf(s.w + b.w, 0.f));
    ((ushort4*)h1b)[((size_t)node * 512 + c) >> 2] = o;
}

// ---------- MFMA GEMM: C[M][512] = A[M][K](bf16) @ Bt[512][K](bf16)^T ----------
// EPI 0: Cf = acc                      (y = x@W1, no bias)
// EPI 1: Cf = acc+bias; Cb = bf16(Cf)  (h = h1@W2+b2, dual store)
// EPI 2: alpha[row] += sum_col tanh(acc+bias)*Wa[col]   (gating, fused)
template <int KDIM, int EPI>
__global__ __launch_bounds__(256) void gemm_bt(const unsigned short* __restrict__ A,
                                               const unsigned short* __restrict__ Bt,
                                               const float* __restrict__ bias,
                                               float* __restrict__ Cf,
                                               unsigned short* __restrict__ Cb,
                                               const float* __restrict__ Wa,
                                               float* __restrict__ alphaOut,
                                               int M) {
    constexpr int BM = 128, BN = 128, BK = 32;
    __shared__ __align__(16) unsigned short As[BM * BK];  // 8 KB
    __shared__ __align__(16) unsigned short Bs[BN * BK];  // 8 KB

    const int tid = threadIdx.x;
    const int lane = tid & 63;
    const int wv = tid >> 6;          // 4 waves, 2x2
    const int wm = wv >> 1, wn = wv & 1;
    const long row0 = (long)blockIdx.x * BM;
    const int col0 = blockIdx.y * BN;

    f32x4 acc[4][4];
#pragma unroll
    for (int m = 0; m < 4; m++)
#pragma unroll
        for (int n = 0; n < 4; n++)
#pragma unroll
            for (int r = 0; r < 4; r++) acc[m][n][r] = 0.f;

    const int sr = tid >> 2;
    const int sk = tid & 3;
    const char* Ab = (const char*)A;
    const char* Bb = (const char*)Bt;
    const unsigned long stride = (unsigned long)KDIM * 2;

    for (int k0 = 0; k0 < KDIM; k0 += BK) {
        __syncthreads();
#pragma unroll
        for (int c = 0; c < 2; c++) {
            long ar = row0 + c * 64 + sr;
            if (ar > M - 1) ar = M - 1;
            const void* ga = Ab + (unsigned long)ar * stride + (unsigned long)k0 * 2 + sk * 16;
            __builtin_amdgcn_global_load_lds(
                (const __attribute__((address_space(1))) void*)ga,
                (__attribute__((address_space(3))) void*)((char*)As + c * 4096 + wv * 1024),
                16, 0, 0);
            long br = col0 + c * 64 + sr;
            const void* gb = Bb + (unsigned long)br * stride + (unsigned long)k0 * 2 + sk * 16;
            __builtin_amdgcn_global_load_lds(
                (const __attribute__((address_space(1))) void*)gb,
                (__attribute__((address_space(3))) void*)((char*)Bs + c * 4096 + wv * 1024),
                16, 0, 0);
        }
        __syncthreads();

        const int kb = (lane >> 4) * 16;
        const int fr = lane & 15;
        bf16x8 af[4], bfr[4];
#pragma unroll
        for (int m = 0; m < 4; m++)
            af[m] = *(const bf16x8*)((const char*)As + (wm * 64 + m * 16 + fr) * 64 + kb);
#pragma unroll
        for (int n = 0; n < 4; n++)
            bfr[n] = *(const bf16x8*)((const char*)Bs + (wn * 64 + n * 16 + fr) * 64 + kb);
#pragma unroll
        for (int m = 0; m < 4; m++)
#pragma unroll
            for (int n = 0; n < 4; n++)
                acc[m][n] = __builtin_amdgcn_mfma_f32_16x16x32_bf16(af[m], bfr[n], acc[m][n], 0, 0, 0);
    }

    if constexpr (EPI != 2) {
#pragma unroll
        for (int m = 0; m < 4; m++)
#pragma unroll
            for (int r = 0; r < 4; r++) {
                long grow = row0 + wm * 64 + m * 16 + ((lane >> 4) << 2) + r;
                if (grow < M) {
#pragma unroll
                    for (int n = 0; n < 4; n++) {
                        int col = col0 + wn * 64 + n * 16 + (lane & 15);
                        float v = acc[m][n][r];
                        if constexpr (EPI == 1) v += bias[col];
                        Cf[(size_t)grow * 512 + col] = v;
                        if constexpr (EPI == 1) Cb[(size_t)grow * 512 + col] = f2b(v);
                    }
                }
            }
    } else {
        float part[4][4];
#pragma unroll
        for (int m = 0; m < 4; m++)
#pragma unroll
            for (int r = 0; r < 4; r++) part[m][r] = 0.f;
#pragma unroll
        for (int n = 0; n < 4; n++) {
            int col = col0 + wn * 64 + n * 16 + (lane & 15);
            float w = Wa[col];
            float bb = bias[col];
#pragma unroll
            for (int m = 0; m < 4; m++)
#pragma unroll
                for (int r = 0; r < 4; r++)
                    part[m][r] += tanhf(acc[m][n][r] + bb) * w;
        }
#pragma unroll
        for (int m = 0; m < 4; m++)
#pragma unroll
            for (int r = 0; r < 4; r++) {
                float s = part[m][r];
#pragma unroll
                for (int o = 1; o < 16; o <<= 1) s += __shfl_xor(s, o, 64);
                if ((lane & 15) == 0) {
                    long grow = row0 + wm * 64 + m * 16 + ((lane >> 4) << 2) + r;
                    if (grow < M) atomicAdd(&alphaOut[grow], s);
                }
            }
    }
}

// ---------- softmax over 20000 scalars (ba cancels) ----------
__global__ __launch_bounds__(1024) void softmax_kernel(const float* __restrict__ alpha,
                                                       float* __restrict__ att, int N) {
    __shared__ float red[16];
    __shared__ float bc[2];
    int tid = threadIdx.x, lane = tid & 63, wv = tid >> 6;
    float m = -3.4e38f;
    for (int i = tid; i < N; i += 1024) m = fmaxf(m, alpha[i]);
#pragma unroll
    for (int o = 32; o > 0; o >>= 1) m = fmaxf(m, __shfl_xor(m, o, 64));
    if (lane == 0) red[wv] = m;
    __syncthreads();
    if (tid == 0) {
        float mm = red[0];
        for (int i = 1; i < 16; i++) mm = fmaxf(mm, red[i]);
        bc[0] = mm;
    }
    __syncthreads();
    float Mx = bc[0];
    float s = 0.f;
    for (int i = tid; i < N; i += 1024) s += expf(alpha[i] - Mx);
#pragma unroll
    for (int o = 32; o > 0; o >>= 1) s += __shfl_xor(s, o, 64);
    if (lane == 0) red[wv] = s;
    __syncthreads();
    if (tid == 0) {
        float ss = 0.f;
        for (int i = 0; i < 16; i++) ss += red[i];
        bc[1] = ss;
    }
    __syncthreads();
    float inv = 1.f / bc[1];
    for (int i = tid; i < N; i += 1024) att[i] = expf(alpha[i] - Mx) * inv;
}

// ---------- launch ----------
extern "C" void kernel_launch(void* const* d_in, const int* in_sizes, int n_in,
                              void* d_out, int out_size, void* d_ws, size_t ws_size,
                              hipStream_t stream) {
    const float* x  = (const float*)d_in[0];
    const int*   ei = (const int*)d_in[1];     // [2][160000]: src then dst
    const float* W1 = (const float*)d_in[2];
    const float* b1 = (const float*)d_in[3];
    const float* W2 = (const float*)d_in[4];
    const float* b2 = (const float*)d_in[5];
    const float* Wg = (const float*)d_in[6];
    const float* bg = (const float*)d_in[7];
    const float* Wa = (const float*)d_in[8];
    // d_in[9] = ba: cancels in softmax, unused.

    const int M = 20000, IN = 2048, H = 512, E = 160000;

    char* ws = (char*)d_ws;
    // x_b occupies [0, 81.92MB); dead after GEMM1. CSR arrays alias it
    // (all CSR kernels are stream-ordered after GEMM1).
    unsigned short* x_b  = (unsigned short*)ws;                    //  81,920,000
    int* counts = (int*)ws;                                        //      80,000 (alias)
    int* offs   = (int*)(ws + 80000);                              //      80,004 (alias)
    int* cursor = (int*)(ws + 160008);                             //      80,000 (alias)
    int* eids   = (int*)(ws + 240008);                             //     640,000 (alias)
    float*          y    = (float*)(ws + 81920000);                //  40,960,000
    unsigned short* W1t  = (unsigned short*)(ws + 122880000);      //   2,097,152
    unsigned short* W2t  = (unsigned short*)(ws + 124977152);      //     524,288
    unsigned short* Wgt  = (unsigned short*)(ws + 125501440);      //     524,288
    unsigned short* h1b  = (unsigned short*)(ws + 126025728);      //  20,480,000
    unsigned short* hb   = (unsigned short*)(ws + 146505728);      //  20,480,000
    float*          alpha= (float*)(ws + 166985728);               //      80,000

    float* hout = (float*)d_out;                 // [20000][512] f32
    float* att  = hout + (size_t)M * H;          // [20000] f32

    // 1) conversions
    conv_x_kernel<<<40000, 256, 0, stream>>>(x, x_b, (long)M * IN / 4);
    convw_kernel<<<4096, 256, 0, stream>>>(W1, W1t, IN, H);
    convw_kernel<<<1024, 256, 0, stream>>>(W2, W2t, H, H);
    convw_kernel<<<1024, 256, 0, stream>>>(Wg, Wgt, H, H);

    // 2) y = x @ W1   (42 GFLOP, bf16 MFMA)
    gemm_bt<2048, 0><<<dim3(157, 4), 256, 0, stream>>>(x_b, W1t, nullptr, y, nullptr, nullptr, nullptr, M);

    // 3) CSR build by dst (aliases dead x_b region)
    hipMemsetAsync(counts, 0, M * 4, stream);
    count_kernel<<<(E + 255) / 256, 256, 0, stream>>>(ei + E, counts, E);
    scan_kernel<<<1, 1024, 0, stream>>>(counts, offs, M);
    hipMemsetAsync(cursor, 0, M * 4, stream);
    bucket_kernel<<<(E + 255) / 256, 256, 0, stream>>>(ei, ei + E, offs, cursor, eids, E);

    // 4) h1 = bf16(relu(y_self + gather(y) + b1))  — fused gather
    gather_h1_kernel<<<10000, 256, 0, stream>>>(y, offs, eids, b1, h1b, M);

    // 5) h = h1 @ W2 + b2  (f32 -> d_out, bf16 copy -> hb)
    gemm_bt<512, 1><<<dim3(157, 4), 256, 0, stream>>>(h1b, W2t, b2, hout, hb, nullptr, nullptr, M);

    // 6) alpha = rowsum(tanh(h @ Wg + bg) * Wa)   (fused epilogue)
    hipMemsetAsync(alpha, 0, M * 4, stream);
    gemm_bt<512, 2><<<dim3(157, 4), 256, 0, stream>>>(hb, Wgt, bg, nullptr, nullptr, Wa, alpha, M);

    // 7) att = softmax(alpha)
    softmax_kernel<<<1, 1024, 0, stream>>>(alpha, att, M);
}

// Round 3
// 330.645 us; speedup vs baseline: 4.0195x; 1.0475x over previous
//
#include <hip/hip_runtime.h>

// ---------- types ----------
typedef __attribute__((ext_vector_type(8))) __bf16 bf16x8;
typedef __attribute__((ext_vector_type(4))) float f32x4;

__device__ __forceinline__ unsigned short f2b(float f) {
    union { float f; unsigned u; } v; v.f = f;
    unsigned r = v.u + 0x7FFFu + ((v.u >> 16) & 1u);   // RNE
    return (unsigned short)(r >> 16);
}

// ---------- W [K][N] f32 -> Wt [N][K] bf16 ----------
__global__ __launch_bounds__(256) void convw_kernel(const float* __restrict__ W,
                                                    unsigned short* __restrict__ Wt,
                                                    int K, int N) {
    int t = blockIdx.x * 256 + threadIdx.x;
    if (t >= K * N) return;
    int k = t / N, n = t - k * N;
    Wt[(size_t)n * K + k] = f2b(W[t]);
}

// ---------- CSR build (by dst) ----------
__global__ __launch_bounds__(256) void count_kernel(const int* __restrict__ dst,
                                                    int* __restrict__ counts, int E) {
    int e = blockIdx.x * 256 + threadIdx.x;
    if (e < E) atomicAdd(&counts[dst[e]], 1);
}

__global__ __launch_bounds__(1024) void scan_kernel(const int* __restrict__ counts,
                                                    int* __restrict__ offs, int N) {
    __shared__ int wsum[16], wpre[16];
    const int CH = 20;
    int tid = threadIdx.x, lane = tid & 63, wv = tid >> 6;
    int base = tid * CH;
    int s = 0;
    for (int i = 0; i < CH; i++) { int idx = base + i; s += (idx < N) ? counts[idx] : 0; }
    int run = s;
#pragma unroll
    for (int o = 1; o < 64; o <<= 1) { int v = __shfl_up(run, o, 64); if (lane >= o) run += v; }
    if (lane == 63) wsum[wv] = run;
    __syncthreads();
    if (tid == 0) { int acc = 0; for (int w = 0; w < 16; w++) { wpre[w] = acc; acc += wsum[w]; } }
    __syncthreads();
    int pre = wpre[wv] + (run - s);
    for (int i = 0; i < CH; i++) {
        int idx = base + i;
        if (idx <= N) offs[idx] = pre;
        pre += (idx < N) ? counts[idx] : 0;
    }
}

__global__ __launch_bounds__(256) void bucket_kernel(const int* __restrict__ src,
                                                     const int* __restrict__ dst,
                                                     const int* __restrict__ offs,
                                                     int* __restrict__ cursor,
                                                     int* __restrict__ eids, int E) {
    int e = blockIdx.x * 256 + threadIdx.x;
    if (e >= E) return;
    int d = dst[e];
    int pos = atomicAdd(&cursor[d], 1);
    eids[offs[d] + pos] = src[e];
}

// ---------- gather + h1: h1 = bf16(relu(y[i] + sum_j y[nbr] + b1)) ----------
__global__ __launch_bounds__(256) void gather_h1_kernel(const float* __restrict__ y,
                                                        const int* __restrict__ offs,
                                                        const int* __restrict__ eids,
                                                        const float* __restrict__ b1,
                                                        unsigned short* __restrict__ h1b,
                                                        int N) {
    int node = blockIdx.x * 2 + (threadIdx.x >> 7);
    if (node >= N) return;
    int c = (threadIdx.x & 127) << 2;
    float4 s = *(const float4*)(y + (size_t)node * 512 + c);
    int beg = offs[node], end = offs[node + 1];
    for (int k = beg; k < end; k++) {
        int sn = eids[k];
        const float4 v = *(const float4*)(y + (size_t)sn * 512 + c);
        s.x += v.x; s.y += v.y; s.z += v.z; s.w += v.w;
    }
    const float4 b = *(const float4*)(b1 + c);
    ushort4 o;
    o.x = f2b(fmaxf(s.x + b.x, 0.f));
    o.y = f2b(fmaxf(s.y + b.y, 0.f));
    o.z = f2b(fmaxf(s.z + b.z, 0.f));
    o.w = f2b(fmaxf(s.w + b.w, 0.f));
    ((ushort4*)h1b)[((size_t)node * 512 + c) >> 2] = o;
}

// =====================================================================
// GEMM1: Y[M][512] = X[M][2048](f32, converted in staging) @ W1t[512][2048]^T
// Swapped MFMA: D = Wfrag * Xfrag -> lane holds D[outcol=(lane>>4)*4+r][node=lane&15]
// BM=64 nodes, BN=512 (all cols), BK=32, 512 thr / 8 waves, 2-phase dbuf.
// LDS (dynamic 73728B): As[2][64*32]bf16 @0 (stride 4096), Bs[2][512*32] @8192 (stride 32768)
// =====================================================================
template <int KDIM>
__global__ __launch_bounds__(512) void gemm1_kernel(const float* __restrict__ X,
                                                    const unsigned short* __restrict__ Wt,
                                                    float* __restrict__ Y, int M) {
    extern __shared__ char smem[];
    const int tid = threadIdx.x, lane = tid & 63, wv = tid >> 6;
    const long row0 = (long)blockIdx.x * 64;

    f32x4 acc[4][4];
#pragma unroll
    for (int m = 0; m < 4; m++)
#pragma unroll
        for (int n = 0; n < 4; n++)
#pragma unroll
            for (int r = 0; r < 4; r++) acc[m][n][r] = 0.f;

    // A staging: thread t loads float4 of row (t>>3), piece (t&7); cvt -> bf16 ds_write
    const int ar_ = tid >> 3;
    const int ac8 = tid & 7;
    long arow = row0 + ar_; if (arow > (long)M - 1) arow = M - 1;
    const float* Ap = X + arow * KDIM + ac8 * 4;

    // B staging: wave wv stages rows [wv*64, wv*64+64) in 4 chunks of 16 rows
    const int brow = lane >> 2;
    const int bby = (lane & 3) * 16;
    const unsigned long bstride = (unsigned long)KDIM * 2;

#define AS(buf) ((char*)smem + (buf) * 4096)
#define BS(buf) ((char*)smem + 8192 + (buf) * 32768)

    {   // prologue: stage t=0 into buf 0
        float4 a = *(const float4*)Ap;
        ushort4 o; o.x = f2b(a.x); o.y = f2b(a.y); o.z = f2b(a.z); o.w = f2b(a.w);
        *(ushort4*)(AS(0) + ar_ * 64 + ac8 * 8) = o;
#pragma unroll
        for (int c = 0; c < 4; c++) {
            int r = wv * 64 + c * 16 + brow;
            const void* g = (const char*)Wt + (unsigned long)r * bstride + bby;
            __builtin_amdgcn_global_load_lds(
                (const __attribute__((address_space(1))) void*)g,
                (__attribute__((address_space(3))) void*)(BS(0) + (wv * 64 + c * 16) * 64),
                16, 0, 0);
        }
    }
    __syncthreads();

    const int fr = lane & 15;
    const int kb = (lane >> 4) * 16;
    constexpr int NT = KDIM / 32;

    for (int t = 0; t < NT; t++) {
        const int cur = t & 1, nxt = cur ^ 1;
        float4 a;
        const bool more = (t + 1 < NT);
        if (more) {
            const int k0 = (t + 1) * 32;
            a = *(const float4*)(Ap + k0);
#pragma unroll
            for (int c = 0; c < 4; c++) {
                int r = wv * 64 + c * 16 + brow;
                const void* g = (const char*)Wt + (unsigned long)r * bstride + (unsigned long)k0 * 2 + bby;
                __builtin_amdgcn_global_load_lds(
                    (const __attribute__((address_space(1))) void*)g,
                    (__attribute__((address_space(3))) void*)(BS(nxt) + (wv * 64 + c * 16) * 64),
                    16, 0, 0);
            }
        }
        bf16x8 wf[4], xf[4];
#pragma unroll
        for (int m = 0; m < 4; m++)
            wf[m] = *(const bf16x8*)(BS(cur) + (wv * 64 + m * 16 + fr) * 64 + kb);
#pragma unroll
        for (int n = 0; n < 4; n++)
            xf[n] = *(const bf16x8*)(AS(cur) + (n * 16 + fr) * 64 + kb);
#pragma unroll
        for (int m = 0; m < 4; m++)
#pragma unroll
            for (int n = 0; n < 4; n++)
                acc[m][n] = __builtin_amdgcn_mfma_f32_16x16x32_bf16(wf[m], xf[n], acc[m][n], 0, 0, 0);
        if (more) {
            ushort4 o; o.x = f2b(a.x); o.y = f2b(a.y); o.z = f2b(a.z); o.w = f2b(a.w);
            *(ushort4*)(AS(nxt) + ar_ * 64 + ac8 * 8) = o;
        }
        __syncthreads();
    }
#undef AS
#undef BS

    // epilogue: node = n*16+(lane&15), outcols = wv*64+m*16+(lane>>4)*4 + [0..3] contiguous
    const int hi4 = (lane >> 4) * 4;
#pragma unroll
    for (int n = 0; n < 4; n++) {
        long node = row0 + n * 16 + fr;
        if (node < M) {
#pragma unroll
            for (int m = 0; m < 4; m++)
                *(f32x4*)(Y + node * 512 + wv * 64 + m * 16 + hi4) = acc[m][n];
        }
    }
}

// =====================================================================
// Fused: h = h1@W2+b2 (f32 -> Hout, bf16 -> LDS swizzled), then
//        alpha = rowsum(tanh(h@Wg+bg)*Wa) straight from LDS.
// LDS (dynamic 139520B): As[2] @0 (stride 4096), Bs[2] @8192 (stride 32768),
//                        Hs[64][512]bf16 @73728 (XOR-swizzled), aS[64]f32 @139264
// =====================================================================
__global__ __launch_bounds__(512) void mlp2_gate_kernel(
    const unsigned short* __restrict__ H1,   // [M][512] bf16
    const unsigned short* __restrict__ W2t,  // [512][512] bf16 (N-major)
    const float* __restrict__ b2,
    const unsigned short* __restrict__ Wgt,  // [512][512] bf16
    const float* __restrict__ bg,
    const float* __restrict__ Wa,            // [512]
    float* __restrict__ Hout,                // [M][512] f32
    float* __restrict__ alpha,               // [M]
    int M) {
    extern __shared__ char smem[];
    char* Hs = smem + 73728;
    float* aS = (float*)(smem + 139264);
    const int tid = threadIdx.x, lane = tid & 63, wv = tid >> 6;
    const long row0 = (long)blockIdx.x * 64;
    const int fr = lane & 15;
    const int kb = (lane >> 4) * 16;
    const int hi4 = (lane >> 4) * 4;
    const int brow = lane >> 2;
    const int bby = (lane & 3) * 16;

    if (tid < 64) aS[tid] = 0.f;

#define AS(buf) ((char*)smem + (buf) * 4096)
#define BS(buf) ((char*)smem + 8192 + (buf) * 32768)
#define STAGE_A(buf, k0) do { if (wv < 4) {                                          \
        long r_ = row0 + wv * 16 + brow; if (r_ > (long)M - 1) r_ = M - 1;           \
        const void* g_ = (const char*)H1 + (unsigned long)r_ * 1024 + (unsigned long)(k0) * 2 + bby; \
        __builtin_amdgcn_global_load_lds(                                            \
            (const __attribute__((address_space(1))) void*)g_,                       \
            (__attribute__((address_space(3))) void*)(AS(buf) + (wv * 16) * 64), 16, 0, 0); } } while (0)
#define STAGE_B(Wt, buf, k0) do { _Pragma("unroll") for (int c_ = 0; c_ < 4; c_++) { \
        int r_ = wv * 64 + c_ * 16 + brow;                                           \
        const void* g_ = (const char*)(Wt) + (unsigned long)r_ * 1024 + (unsigned long)(k0) * 2 + bby; \
        __builtin_amdgcn_global_load_lds(                                            \
            (const __attribute__((address_space(1))) void*)g_,                       \
            (__attribute__((address_space(3))) void*)(BS(buf) + (wv * 64 + c_ * 16) * 64), 16, 0, 0); } } while (0)

    f32x4 acc[4][4];
#pragma unroll
    for (int m = 0; m < 4; m++)
#pragma unroll
        for (int n = 0; n < 4; n++)
#pragma unroll
            for (int r = 0; r < 4; r++) acc[m][n][r] = 0.f;

    // ---- phase 1: h = h1 @ W2 ----
    STAGE_A(0, 0);
    STAGE_B(W2t, 0, 0);
    __syncthreads();
    for (int t = 0; t < 16; t++) {
        const int cur = t & 1, nxt = cur ^ 1;
        if (t + 1 < 16) { STAGE_A(nxt, (t + 1) * 32); STAGE_B(W2t, nxt, (t + 1) * 32); }
        bf16x8 wf[4], xf[4];
#pragma unroll
        for (int m = 0; m < 4; m++)
            wf[m] = *(const bf16x8*)(BS(cur) + (wv * 64 + m * 16 + fr) * 64 + kb);
#pragma unroll
        for (int n = 0; n < 4; n++)
            xf[n] = *(const bf16x8*)(AS(cur) + (n * 16 + fr) * 64 + kb);
#pragma unroll
        for (int m = 0; m < 4; m++)
#pragma unroll
            for (int n = 0; n < 4; n++)
                acc[m][n] = __builtin_amdgcn_mfma_f32_16x16x32_bf16(wf[m], xf[n], acc[m][n], 0, 0, 0);
        __syncthreads();
    }

    // phase-1 epilogue: Hout f32 store (coalesced f32x4) + Hs bf16 (XOR swizzle (node&7)<<4)
#pragma unroll
    for (int n = 0; n < 4; n++) {
        int node = n * 16 + fr;
        long gnode = row0 + node;
#pragma unroll
        for (int m = 0; m < 4; m++) {
            int hc = wv * 64 + m * 16 + hi4;
            f32x4 bv = *(const f32x4*)(b2 + hc);
            f32x4 v = acc[m][n] + bv;
            if (gnode < M) *(f32x4*)(Hout + gnode * 512 + hc) = v;
            ushort4 o; o.x = f2b(v[0]); o.y = f2b(v[1]); o.z = f2b(v[2]); o.w = f2b(v[3]);
            unsigned boff = (unsigned)(node * 1024 + hc * 2) ^ (unsigned)((node & 7) << 4);
            *(ushort4*)(Hs + boff) = o;
        }
    }

    // ---- phase 2: g = tanh(h @ Wg + bg), alpha = g . Wa ----
    f32x4 acc2[4][4];
#pragma unroll
    for (int m = 0; m < 4; m++)
#pragma unroll
        for (int n = 0; n < 4; n++)
#pragma unroll
            for (int r = 0; r < 4; r++) acc2[m][n][r] = 0.f;

    STAGE_B(Wgt, 0, 0);
    __syncthreads();   // also fences Hs writes
    for (int t = 0; t < 16; t++) {
        const int cur = t & 1, nxt = cur ^ 1;
        if (t + 1 < 16) STAGE_B(Wgt, nxt, (t + 1) * 32);
        bf16x8 wf[4], hf[4];
        const int k0b = t * 64;   // t*32 elems * 2B
#pragma unroll
        for (int m = 0; m < 4; m++)
            wf[m] = *(const bf16x8*)(BS(cur) + (wv * 64 + m * 16 + fr) * 64 + kb);
#pragma unroll
        for (int n = 0; n < 4; n++) {
            int node = n * 16 + fr;
            unsigned boff = (unsigned)(node * 1024 + k0b + kb) ^ (unsigned)((node & 7) << 4);
            hf[n] = *(const bf16x8*)(Hs + boff);
        }
#pragma unroll
        for (int m = 0; m < 4; m++)
#pragma unroll
            for (int n = 0; n < 4; n++)
                acc2[m][n] = __builtin_amdgcn_mfma_f32_16x16x32_bf16(wf[m], hf[n], acc2[m][n], 0, 0, 0);
        __syncthreads();
    }
#undef AS
#undef BS
#undef STAGE_A
#undef STAGE_B

    // epilogue 2: per-lane 16-gate partial, LDS atomic reduce, direct alpha store
#pragma unroll
    for (int n = 0; n < 4; n++) {
        float s = 0.f;
#pragma unroll
        for (int m = 0; m < 4; m++) {
            int g = wv * 64 + m * 16 + hi4;
            f32x4 bgv = *(const f32x4*)(bg + g);
            f32x4 wav = *(const f32x4*)(Wa + g);
#pragma unroll
            for (int r = 0; r < 4; r++)
                s += tanhf(acc2[m][n][r] + bgv[r]) * wav[r];
        }
        atomicAdd(&aS[n * 16 + fr], s);
    }
    __syncthreads();
    if (tid < 64) {
        long node = row0 + tid;
        if (node < M) alpha[node] = aS[tid];
    }
}

// ---------- softmax over 20000 scalars (ba cancels) ----------
__global__ __launch_bounds__(1024) void softmax_kernel(const float* __restrict__ alpha,
                                                       float* __restrict__ att, int N) {
    __shared__ float red[16];
    __shared__ float bc[2];
    int tid = threadIdx.x, lane = tid & 63, wv = tid >> 6;
    float m = -3.4e38f;
    for (int i = tid; i < N; i += 1024) m = fmaxf(m, alpha[i]);
#pragma unroll
    for (int o = 32; o > 0; o >>= 1) m = fmaxf(m, __shfl_xor(m, o, 64));
    if (lane == 0) red[wv] = m;
    __syncthreads();
    if (tid == 0) {
        float mm = red[0];
        for (int i = 1; i < 16; i++) mm = fmaxf(mm, red[i]);
        bc[0] = mm;
    }
    __syncthreads();
    float Mx = bc[0];
    float s = 0.f;
    for (int i = tid; i < N; i += 1024) s += expf(alpha[i] - Mx);
#pragma unroll
    for (int o = 32; o > 0; o >>= 1) s += __shfl_xor(s, o, 64);
    if (lane == 0) red[wv] = s;
    __syncthreads();
    if (tid == 0) {
        float ss = 0.f;
        for (int i = 0; i < 16; i++) ss += red[i];
        bc[1] = ss;
    }
    __syncthreads();
    float inv = 1.f / bc[1];
    for (int i = tid; i < N; i += 1024) att[i] = expf(alpha[i] - Mx) * inv;
}

// ---------- launch ----------
extern "C" void kernel_launch(void* const* d_in, const int* in_sizes, int n_in,
                              void* d_out, int out_size, void* d_ws, size_t ws_size,
                              hipStream_t stream) {
    const float* x  = (const float*)d_in[0];
    const int*   ei = (const int*)d_in[1];     // [2][160000]: src then dst
    const float* W1 = (const float*)d_in[2];
    const float* b1 = (const float*)d_in[3];
    const float* W2 = (const float*)d_in[4];
    const float* b2 = (const float*)d_in[5];
    const float* Wg = (const float*)d_in[6];
    const float* bg = (const float*)d_in[7];
    const float* Wa = (const float*)d_in[8];
    // d_in[9] = ba: cancels in softmax, unused.

    const int M = 20000, IN = 2048, H = 512, E = 160000;

    char* ws = (char*)d_ws;
    float*          y     = (float*)ws;                            // 40,960,000
    unsigned short* W1t   = (unsigned short*)(ws + 40960000);      //  2,097,152
    unsigned short* W2t   = (unsigned short*)(ws + 43057152);      //    524,288
    unsigned short* Wgt   = (unsigned short*)(ws + 43581440);      //    524,288
    unsigned short* h1b   = (unsigned short*)(ws + 44105728);      // 20,480,000
    float*          alpha = (float*)(ws + 64585728);               //     80,000
    int*            counts= (int*)(ws + 64665728);                 //     80,000
    int*            offs  = (int*)(ws + 64745728);                 //     80,004
    int*            cursor= (int*)(ws + 64825732);                 //     80,000
    int*            eids  = (int*)(ws + 64905732);                 //    640,000

    float* hout = (float*)d_out;                 // [20000][512] f32
    float* att  = hout + (size_t)M * H;          // [20000] f32

    // weight transpose+convert (small)
    convw_kernel<<<4096, 256, 0, stream>>>(W1, W1t, IN, H);
    convw_kernel<<<1024, 256, 0, stream>>>(W2, W2t, H, H);
    convw_kernel<<<1024, 256, 0, stream>>>(Wg, Wgt, H, H);

    // CSR build by dst
    hipMemsetAsync(counts, 0, M * 4, stream);
    count_kernel<<<(E + 255) / 256, 256, 0, stream>>>(ei + E, counts, E);
    scan_kernel<<<1, 1024, 0, stream>>>(counts, offs, M);
    hipMemsetAsync(cursor, 0, M * 4, stream);
    bucket_kernel<<<(E + 255) / 256, 256, 0, stream>>>(ei, ei + E, offs, cursor, eids, E);

    // y = x @ W1  (f32 A converted in staging; A read once, BN=512)
    gemm1_kernel<2048><<<313, 512, 73728, stream>>>(x, W1t, y, M);

    // h1 = bf16(relu(y_self + gather(y) + b1))
    gather_h1_kernel<<<10000, 256, 0, stream>>>(y, offs, eids, b1, h1b, M);

    // h = h1@W2+b2 -> d_out + fused alpha = rowsum(tanh(h@Wg+bg)*Wa)
    mlp2_gate_kernel<<<313, 512, 139520, stream>>>(h1b, W2t, b2, Wgt, bg, Wa, hout, alpha, M);

    // att = softmax(alpha)
    softmax_kernel<<<1, 1024, 0, stream>>>(alpha, att, M);
}

// Round 4
// 275.805 us; speedup vs baseline: 4.8187x; 1.1988x over previous
//
#include <hip/hip_runtime.h>

// ---------- types ----------
typedef __attribute__((ext_vector_type(8))) __bf16 bf16x8;
typedef __attribute__((ext_vector_type(4))) float f32x4;
typedef __attribute__((ext_vector_type(8))) unsigned short u16x8;

__device__ __forceinline__ unsigned short f2b(float f) {
    union { float f; unsigned u; } v; v.f = f;
    unsigned r = v.u + 0x7FFFu + ((v.u >> 16) & 1u);   // RNE
    return (unsigned short)(r >> 16);
}

#define GLDS(g, l) __builtin_amdgcn_global_load_lds(                        \
    (const __attribute__((address_space(1))) void*)(g),                     \
    (__attribute__((address_space(3))) void*)(l), 16, 0, 0)

// ---------- W [K][N=512] f32 -> pre-tiled sector layout bf16 ----------
// out byte = (cb*(K/32) + tt)*16384 + s*4096 + r*16 + e*2
//   cb=n>>8, r=n&255, tt=k>>5, s=(k&31)>>3, e=k&7
__global__ __launch_bounds__(256) void convw_pre_kernel(const float* __restrict__ W,
                                                        char* __restrict__ out, int K) {
    int t = blockIdx.x * 256 + threadIdx.x;
    if (t >= K * 512) return;
    int k = t >> 9, n = t & 511;
    int cb = n >> 8, r = n & 255, tt = k >> 5, s = (k & 31) >> 3, e = k & 7;
    size_t off = ((size_t)cb * (K >> 5) + tt) * 16384 + s * 4096 + r * 16 + e * 2;
    *(unsigned short*)(out + off) = f2b(W[t]);
}

// ---------- CSR build (by dst) ----------
__global__ __launch_bounds__(256) void count_kernel(const int* __restrict__ dst,
                                                    int* __restrict__ counts, int E) {
    int e = blockIdx.x * 256 + threadIdx.x;
    if (e < E) atomicAdd(&counts[dst[e]], 1);
}

__global__ __launch_bounds__(1024) void scan_kernel(const int* __restrict__ counts,
                                                    int* __restrict__ offs, int N) {
    __shared__ int wsum[16], wpre[16];
    const int CH = 20;
    int tid = threadIdx.x, lane = tid & 63, wv = tid >> 6;
    int base = tid * CH;
    int s = 0;
    for (int i = 0; i < CH; i++) { int idx = base + i; s += (idx < N) ? counts[idx] : 0; }
    int run = s;
#pragma unroll
    for (int o = 1; o < 64; o <<= 1) { int v = __shfl_up(run, o, 64); if (lane >= o) run += v; }
    if (lane == 63) wsum[wv] = run;
    __syncthreads();
    if (tid == 0) { int acc = 0; for (int w = 0; w < 16; w++) { wpre[w] = acc; acc += wsum[w]; } }
    __syncthreads();
    int pre = wpre[wv] + (run - s);
    for (int i = 0; i < CH; i++) {
        int idx = base + i;
        if (idx <= N) offs[idx] = pre;
        pre += (idx < N) ? counts[idx] : 0;
    }
}

__global__ __launch_bounds__(256) void bucket_kernel(const int* __restrict__ src,
                                                     const int* __restrict__ dst,
                                                     const int* __restrict__ offs,
                                                     int* __restrict__ cursor,
                                                     int* __restrict__ eids, int E) {
    int e = blockIdx.x * 256 + threadIdx.x;
    if (e >= E) return;
    int d = dst[e];
    int pos = atomicAdd(&cursor[d], 1);
    eids[offs[d] + pos] = src[e];
}

// ---------- gather + h1: h1 = bf16(relu(y[i] + sum_j y[nbr] + b1)) ----------
__global__ __launch_bounds__(256) void gather_h1_kernel(const float* __restrict__ y,
                                                        const int* __restrict__ offs,
                                                        const int* __restrict__ eids,
                                                        const float* __restrict__ b1,
                                                        unsigned short* __restrict__ h1b,
                                                        int N) {
    int node = blockIdx.x * 2 + (threadIdx.x >> 7);
    if (node >= N) return;
    int c = (threadIdx.x & 127) << 2;
    float4 s = *(const float4*)(y + (size_t)node * 512 + c);
    int beg = offs[node], end = offs[node + 1];
    for (int k = beg; k < end; k++) {
        int sn = eids[k];
        const float4 v = *(const float4*)(y + (size_t)sn * 512 + c);
        s.x += v.x; s.y += v.y; s.z += v.z; s.w += v.w;
    }
    const float4 b = *(const float4*)(b1 + c);
    ushort4 o;
    o.x = f2b(fmaxf(s.x + b.x, 0.f));
    o.y = f2b(fmaxf(s.y + b.y, 0.f));
    o.z = f2b(fmaxf(s.z + b.z, 0.f));
    o.w = f2b(fmaxf(s.w + b.w, 0.f));
    ((ushort4*)h1b)[((size_t)node * 512 + c) >> 2] = o;
}

// =====================================================================
// Sector-layout GEMM: C[M][512] = A[M][KDIM] @ W[KDIM][512]
// Block: 256 thr (4 waves), BM=64 rows, BN=256 cols (cb=blockIdx.y), BK=32.
// LDS 40960B: A[2][4KB] @0 sector layout (sec*1024+row*16),
//             B[2][16KB] @8192 sector layout (sec*4096+row*16), dbuf.
// AMODE: 0 = A f32 row-major (convert in staging), 1 = A bf16 row-major,
//        2 = A pre-tiled sector (linear global_load_lds from hbpre).
// EPI:   0 = plain f32 store; 1 = +bias, f32 store + pre-tiled bf16 store;
//        2 = alpha[row] += sum tanh(acc+bias)*Wa  (LDS reduce + global atomic).
// Swapped MFMA: D = Wfrag*Afrag; node=lane&15 (B-side), col=(lane>>4)*4+r (A-side).
// =====================================================================
template <int KDIM, int AMODE, int EPI>
__global__ __launch_bounds__(256) void gemm_sec(const void* __restrict__ Asrc,
                                                const char* __restrict__ Bpre,
                                                const float* __restrict__ bias,
                                                float* __restrict__ Cf,
                                                char* __restrict__ hbpre,
                                                const float* __restrict__ Wa,
                                                float* __restrict__ alphaOut,
                                                int M) {
    constexpr int NT = KDIM / 32;
    __shared__ char smem[40960];
    const int tid = threadIdx.x, lane = tid & 63, wv = tid >> 6;
    const int fr = lane & 15, sec = lane >> 4, hi4 = (lane >> 4) * 4;
    const long row0 = (long)blockIdx.x * 64;
    const int cb = blockIdx.y;
    const char* Bp = Bpre + (size_t)cb * NT * 16384;

    f32x4 acc[4][4];
#pragma unroll
    for (int m = 0; m < 4; m++)
#pragma unroll
        for (int n = 0; n < 4; n++)
#pragma unroll
            for (int r = 0; r < 4; r++) acc[m][n][r] = 0.f;

    const int as_ = tid & 3, ar_ = tid >> 2;
    long arow = row0 + ar_; if (arow > (long)M - 1) arow = M - 1;
    const float* ApF = (const float*)Asrc + arow * KDIM + as_ * 8;       // AMODE 0
    const char*  ApH = (const char*)Asrc + arow * (KDIM * 2) + as_ * 16; // AMODE 1
    const char*  ApT = (const char*)Asrc + (size_t)blockIdx.x * 65536;   // AMODE 2

#define ASEC(b) (smem + (b) * 4096)
#define BSEC(b) (smem + 8192 + (b) * 16384)
#define STAGE_B(buf, t) do {                                              \
        const char* src_ = Bp + (size_t)(t) * 16384;                      \
        _Pragma("unroll") for (int c_ = 0; c_ < 4; c_++)                  \
            GLDS(src_ + tid * 16 + c_ * 4096, BSEC(buf) + tid * 16 + c_ * 4096); \
    } while (0)

    // prologue: stage tile 0 into buf 0
    STAGE_B(0, 0);
    if constexpr (AMODE == 0) {
        float4 a0 = *(const float4*)(ApF), a1 = *(const float4*)(ApF + 4);
        u16x8 o; o[0]=f2b(a0.x); o[1]=f2b(a0.y); o[2]=f2b(a0.z); o[3]=f2b(a0.w);
        o[4]=f2b(a1.x); o[5]=f2b(a1.y); o[6]=f2b(a1.z); o[7]=f2b(a1.w);
        *(u16x8*)(ASEC(0) + as_ * 1024 + ar_ * 16) = o;
    } else if constexpr (AMODE == 1) {
        u16x8 v = *(const u16x8*)(ApH);
        *(u16x8*)(ASEC(0) + as_ * 1024 + ar_ * 16) = v;
    } else {
        GLDS(ApT + tid * 16, ASEC(0) + tid * 16);
    }
    __syncthreads();

    for (int t = 0; t < NT; t++) {
        const int cur = t & 1, nxt = cur ^ 1;
        const bool more = (t + 1 < NT);
        float4 a0, a1; u16x8 av;
        if (more) {
            STAGE_B(nxt, t + 1);
            if constexpr (AMODE == 0) {
                a0 = *(const float4*)(ApF + (t + 1) * 32);
                a1 = *(const float4*)(ApF + (t + 1) * 32 + 4);
            } else if constexpr (AMODE == 1) {
                av = *(const u16x8*)(ApH + (t + 1) * 64);
            } else {
                GLDS(ApT + (size_t)(t + 1) * 4096 + tid * 16, ASEC(nxt) + tid * 16);
            }
        }
        bf16x8 wf[4], xf[4];
#pragma unroll
        for (int m = 0; m < 4; m++)
            wf[m] = *(const bf16x8*)(BSEC(cur) + sec * 4096 + (wv * 64 + m * 16 + fr) * 16);
#pragma unroll
        for (int n = 0; n < 4; n++)
            xf[n] = *(const bf16x8*)(ASEC(cur) + sec * 1024 + (n * 16 + fr) * 16);
#pragma unroll
        for (int m = 0; m < 4; m++)
#pragma unroll
            for (int n = 0; n < 4; n++)
                acc[m][n] = __builtin_amdgcn_mfma_f32_16x16x32_bf16(wf[m], xf[n], acc[m][n], 0, 0, 0);
        if (more) {
            if constexpr (AMODE == 0) {
                u16x8 o; o[0]=f2b(a0.x); o[1]=f2b(a0.y); o[2]=f2b(a0.z); o[3]=f2b(a0.w);
                o[4]=f2b(a1.x); o[5]=f2b(a1.y); o[6]=f2b(a1.z); o[7]=f2b(a1.w);
                *(u16x8*)(ASEC(nxt) + as_ * 1024 + ar_ * 16) = o;
            } else if constexpr (AMODE == 1) {
                *(u16x8*)(ASEC(nxt) + as_ * 1024 + ar_ * 16) = av;
            }
        }
        __syncthreads();
    }

    if constexpr (EPI == 0) {
#pragma unroll
        for (int n = 0; n < 4; n++) {
            long node = row0 + n * 16 + fr;
            if (node < M) {
#pragma unroll
                for (int m = 0; m < 4; m++)
                    *(f32x4*)(Cf + node * 512 + cb * 256 + wv * 64 + m * 16 + hi4) = acc[m][n];
            }
        }
    } else if constexpr (EPI == 1) {
#pragma unroll
        for (int n = 0; n < 4; n++) {
            int nodeloc = n * 16 + fr;
            long node = row0 + nodeloc;
#pragma unroll
            for (int m = 0; m < 4; m++) {
                int hc = cb * 256 + wv * 64 + m * 16 + hi4;
                f32x4 bv = *(const f32x4*)(bias + hc);
                f32x4 v = acc[m][n] + bv;
                if (node < M) *(f32x4*)(Cf + node * 512 + hc) = v;
                ushort4 o; o.x = f2b(v[0]); o.y = f2b(v[1]); o.z = f2b(v[2]); o.w = f2b(v[3]);
                int tt = hc >> 5, ss = (hc & 31) >> 3, e = hc & 7;
                *(ushort4*)(hbpre + (size_t)blockIdx.x * 65536 + tt * 4096 + ss * 1024 + nodeloc * 16 + e * 2) = o;
            }
        }
    } else {
        float* aS = (float*)smem;          // A/B buffers dead after last barrier
        if (tid < 64) aS[tid] = 0.f;
        __syncthreads();
#pragma unroll
        for (int n = 0; n < 4; n++) {
            float s = 0.f;
#pragma unroll
            for (int m = 0; m < 4; m++) {
                int gc = cb * 256 + wv * 64 + m * 16 + hi4;
                f32x4 bgv = *(const f32x4*)(bias + gc);
                f32x4 wav = *(const f32x4*)(Wa + gc);
#pragma unroll
                for (int r = 0; r < 4; r++)
                    s += tanhf(acc[m][n][r] + bgv[r]) * wav[r];
            }
            atomicAdd(&aS[n * 16 + fr], s);
        }
        __syncthreads();
        if (tid < 64) {
            long node = row0 + tid;
            if (node < M) atomicAdd(&alphaOut[node], aS[tid]);
        }
    }
#undef ASEC
#undef BSEC
#undef STAGE_B
}

// ---------- softmax over 20000 scalars (ba cancels) ----------
__global__ __launch_bounds__(1024) void softmax_kernel(const float* __restrict__ alpha,
                                                       float* __restrict__ att, int N) {
    __shared__ float red[16];
    __shared__ float bc[2];
    int tid = threadIdx.x, lane = tid & 63, wv = tid >> 6;
    float m = -3.4e38f;
    for (int i = tid; i < N; i += 1024) m = fmaxf(m, alpha[i]);
#pragma unroll
    for (int o = 32; o > 0; o >>= 1) m = fmaxf(m, __shfl_xor(m, o, 64));
    if (lane == 0) red[wv] = m;
    __syncthreads();
    if (tid == 0) {
        float mm = red[0];
        for (int i = 1; i < 16; i++) mm = fmaxf(mm, red[i]);
        bc[0] = mm;
    }
    __syncthreads();
    float Mx = bc[0];
    float s = 0.f;
    for (int i = tid; i < N; i += 1024) s += expf(alpha[i] - Mx);
#pragma unroll
    for (int o = 32; o > 0; o >>= 1) s += __shfl_xor(s, o, 64);
    if (lane == 0) red[wv] = s;
    __syncthreads();
    if (tid == 0) {
        float ss = 0.f;
        for (int i = 0; i < 16; i++) ss += red[i];
        bc[1] = ss;
    }
    __syncthreads();
    float inv = 1.f / bc[1];
    for (int i = tid; i < N; i += 1024) att[i] = expf(alpha[i] - Mx) * inv;
}

// ---------- launch ----------
extern "C" void kernel_launch(void* const* d_in, const int* in_sizes, int n_in,
                              void* d_out, int out_size, void* d_ws, size_t ws_size,
                              hipStream_t stream) {
    const float* x  = (const float*)d_in[0];
    const int*   ei = (const int*)d_in[1];     // [2][160000]: src then dst
    const float* W1 = (const float*)d_in[2];
    const float* b1 = (const float*)d_in[3];
    const float* W2 = (const float*)d_in[4];
    const float* b2 = (const float*)d_in[5];
    const float* Wg = (const float*)d_in[6];
    const float* bg = (const float*)d_in[7];
    const float* Wa = (const float*)d_in[8];
    // d_in[9] = ba: cancels in softmax, unused.

    const int M = 20000, IN = 2048, H = 512, E = 160000;

    char* ws = (char*)d_ws;
    float* y      = (float*)ws;                 // 40,960,000
    char*  W1p    = ws + 40960000;              //  2,097,152
    char*  W2p    = ws + 43057152;              //    524,288
    char*  Wgp    = ws + 43581440;              //    524,288
    unsigned short* h1b = (unsigned short*)(ws + 44105728);  // 20,480,000
    char*  hbpre  = ws + 64585728;              // 20,512,768 (313*65536)
    float* alpha  = (float*)(ws + 85098496);    //     80,000
    int*   counts = (int*)(ws + 85178496);      //     80,000
    int*   offs   = (int*)(ws + 85258496);      //     80,004
    int*   cursor = (int*)(ws + 85338504);      //     80,000
    int*   eids   = (int*)(ws + 85418504);      //    640,000

    float* hout = (float*)d_out;                 // [20000][512] f32
    float* att  = hout + (size_t)M * H;          // [20000] f32

    // weights -> pre-tiled sector layout (bf16)
    convw_pre_kernel<<<4096, 256, 0, stream>>>(W1, W1p, IN);
    convw_pre_kernel<<<1024, 256, 0, stream>>>(W2, W2p, H);
    convw_pre_kernel<<<1024, 256, 0, stream>>>(Wg, Wgp, H);

    // CSR build by dst
    hipMemsetAsync(counts, 0, M * 4, stream);
    count_kernel<<<(E + 255) / 256, 256, 0, stream>>>(ei + E, counts, E);
    scan_kernel<<<1, 1024, 0, stream>>>(counts, offs, M);
    hipMemsetAsync(cursor, 0, M * 4, stream);
    bucket_kernel<<<(E + 255) / 256, 256, 0, stream>>>(ei, ei + E, offs, cursor, eids, E);

    // y = x @ W1
    gemm_sec<2048, 0, 0><<<dim3(313, 2), 256, 0, stream>>>(x, W1p, nullptr, y, nullptr, nullptr, nullptr, M);

    // h1 = bf16(relu(y_self + gather(y) + b1))
    gather_h1_kernel<<<10000, 256, 0, stream>>>(y, offs, eids, b1, h1b, M);

    // h = h1@W2+b2 -> hout (f32) + hbpre (bf16, pre-tiled)
    gemm_sec<512, 1, 1><<<dim3(313, 2), 256, 0, stream>>>(h1b, W2p, b2, hout, hbpre, nullptr, nullptr, M);

    // alpha = rowsum(tanh(h@Wg+bg)*Wa), split over 2 col-blocks via atomics
    hipMemsetAsync(alpha, 0, M * 4, stream);
    gemm_sec<512, 2, 2><<<dim3(313, 2), 256, 0, stream>>>(hbpre, Wgp, bg, nullptr, nullptr, Wa, alpha, M);

    // att = softmax(alpha)
    softmax_kernel<<<1, 1024, 0, stream>>>(alpha, att, M);
}

// Round 5
// 273.174 us; speedup vs baseline: 4.8651x; 1.0096x over previous
//
#include <hip/hip_runtime.h>

// ---------- types ----------
typedef __attribute__((ext_vector_type(8))) __bf16 bf16x8;
typedef __attribute__((ext_vector_type(4))) float f32x4;
typedef __attribute__((ext_vector_type(8))) unsigned short u16x8;

__device__ __forceinline__ unsigned short f2b(float f) {
    union { float f; unsigned u; } v; v.f = f;
    unsigned r = v.u + 0x7FFFu + ((v.u >> 16) & 1u);   // RNE
    return (unsigned short)(r >> 16);
}

// m201 st_16x32 swizzle on 64B rows: flips byte-bit5 with row-bit3.
__device__ __forceinline__ unsigned swz(int row, int s) {
    return (unsigned)((row * 64 + s * 16) ^ ((row & 8) << 2));
}

#define GLDS(g, l) __builtin_amdgcn_global_load_lds(                        \
    (const __attribute__((address_space(1))) void*)(g),                     \
    (__attribute__((address_space(3))) void*)(l), 16, 0, 0)

// ---------- W [K][N=512] f32 -> pre-tiled + pre-swizzled bf16 image ----------
// tile (cb, tt) holds cols cb*256..+255 x K-rows tt*32..+31 as the exact
// 16KB LDS image: byte = swz(r = n&255, s=(k&31)>>3) + (k&7)*2
__global__ __launch_bounds__(256) void convw_pre_kernel(const float* __restrict__ W,
                                                        char* __restrict__ out, int K) {
    int t = blockIdx.x * 256 + threadIdx.x;
    if (t >= K * 512) return;
    int k = t >> 9, n = t & 511;
    int cb = n >> 8, r = n & 255, tt = k >> 5, s = (k & 31) >> 3, e = k & 7;
    size_t off = ((size_t)cb * (K >> 5) + tt) * 16384 + swz(r, s) + e * 2;
    *(unsigned short*)(out + off) = f2b(W[t]);
}

// ---------- CSR build (by dst) ----------
__global__ __launch_bounds__(256) void count_kernel(const int* __restrict__ dst,
                                                    int* __restrict__ counts, int E) {
    int e = blockIdx.x * 256 + threadIdx.x;
    if (e < E) atomicAdd(&counts[dst[e]], 1);
}

__global__ __launch_bounds__(1024) void scan_kernel(const int* __restrict__ counts,
                                                    int* __restrict__ offs, int N) {
    __shared__ int wsum[16], wpre[16];
    const int CH = 20;
    int tid = threadIdx.x, lane = tid & 63, wv = tid >> 6;
    int base = tid * CH;
    int s = 0;
    for (int i = 0; i < CH; i++) { int idx = base + i; s += (idx < N) ? counts[idx] : 0; }
    int run = s;
#pragma unroll
    for (int o = 1; o < 64; o <<= 1) { int v = __shfl_up(run, o, 64); if (lane >= o) run += v; }
    if (lane == 63) wsum[wv] = run;
    __syncthreads();
    if (tid == 0) { int acc = 0; for (int w = 0; w < 16; w++) { wpre[w] = acc; acc += wsum[w]; } }
    __syncthreads();
    int pre = wpre[wv] + (run - s);
    for (int i = 0; i < CH; i++) {
        int idx = base + i;
        if (idx <= N) offs[idx] = pre;
        pre += (idx < N) ? counts[idx] : 0;
    }
}

__global__ __launch_bounds__(256) void bucket_kernel(const int* __restrict__ src,
                                                     const int* __restrict__ dst,
                                                     const int* __restrict__ offs,
                                                     int* __restrict__ cursor,
                                                     int* __restrict__ eids, int E) {
    int e = blockIdx.x * 256 + threadIdx.x;
    if (e >= E) return;
    int d = dst[e];
    int pos = atomicAdd(&cursor[d], 1);
    eids[offs[d] + pos] = src[e];
}

// ---------- gather + h1: h1 = bf16(relu(y[i] + sum_j y[nbr] + b1)) ----------
__global__ __launch_bounds__(256) void gather_h1_kernel(const float* __restrict__ y,
                                                        const int* __restrict__ offs,
                                                        const int* __restrict__ eids,
                                                        const float* __restrict__ b1,
                                                        unsigned short* __restrict__ h1b,
                                                        int N) {
    int node = blockIdx.x * 2 + (threadIdx.x >> 7);
    if (node >= N) return;
    int c = (threadIdx.x & 127) << 2;
    float4 s = *(const float4*)(y + (size_t)node * 512 + c);
    int beg = offs[node], end = offs[node + 1];
    for (int k = beg; k < end; k++) {
        int sn = eids[k];
        const float4 v = *(const float4*)(y + (size_t)sn * 512 + c);
        s.x += v.x; s.y += v.y; s.z += v.z; s.w += v.w;
    }
    const float4 b = *(const float4*)(b1 + c);
    ushort4 o;
    o.x = f2b(fmaxf(s.x + b.x, 0.f));
    o.y = f2b(fmaxf(s.y + b.y, 0.f));
    o.z = f2b(fmaxf(s.z + b.z, 0.f));
    o.w = f2b(fmaxf(s.w + b.w, 0.f));
    ((ushort4*)h1b)[((size_t)node * 512 + c) >> 2] = o;
}

// =====================================================================
// Swizzled-tile GEMM: C[M][512] = A[M][KDIM] @ W[KDIM][512]
// Block: 256 thr (4 waves), BM=64 rows, BN=256 cols (cb=blockIdx.y), BK=32.
// LDS 40960B: A[2][4KB] @0, B[2][16KB] @8192 — both st_16x32-swizzled 64B rows.
// AMODE: 0 = A f32 row-major (convert in staging), 1 = A bf16 row-major,
//        2 = A pre-tiled+swizzled (linear global_load_lds from hbpre).
// EPI:   0 = plain f32 store; 1 = +bias, f32 store + pre-tiled bf16 store;
//        2 = alpha[row] += sum tanh(acc+bias)*Wa  (LDS reduce + global atomic).
// Swapped MFMA: D = Wfrag*Afrag; node=lane&15, weightcol=(lane>>4)*4+r.
// =====================================================================
template <int KDIM, int AMODE, int EPI>
__global__ __launch_bounds__(256) void gemm_sec(const void* __restrict__ Asrc,
                                                const char* __restrict__ Bpre,
                                                const float* __restrict__ bias,
                                                float* __restrict__ Cf,
                                                char* __restrict__ hbpre,
                                                const float* __restrict__ Wa,
                                                float* __restrict__ alphaOut,
                                                int M) {
    constexpr int NT = KDIM / 32;
    __shared__ char smem[40960];
    const int tid = threadIdx.x, lane = tid & 63, wv = tid >> 6;
    const int fr = lane & 15, sec = lane >> 4, hi4 = (lane >> 4) * 4;
    const long row0 = (long)blockIdx.x * 64;
    const int cb = blockIdx.y;
    const char* Bp = Bpre + (size_t)cb * NT * 16384;

    f32x4 acc[4][4];
#pragma unroll
    for (int m = 0; m < 4; m++)
#pragma unroll
        for (int n = 0; n < 4; n++)
#pragma unroll
            for (int r = 0; r < 4; r++) acc[m][n][r] = 0.f;

    const int as_ = tid & 3, ar_ = tid >> 2;
    const unsigned awz = swz(ar_, as_);
    long arow = row0 + ar_; if (arow > (long)M - 1) arow = M - 1;
    const float* ApF = (const float*)Asrc + arow * KDIM + as_ * 8;       // AMODE 0
    const char*  ApH = (const char*)Asrc + arow * (KDIM * 2) + as_ * 16; // AMODE 1
    const char*  ApT = (const char*)Asrc + (size_t)blockIdx.x * 65536;   // AMODE 2

#define ASEC(b) (smem + (b) * 4096)
#define BSEC(b) (smem + 8192 + (b) * 16384)
#define STAGE_B(buf, t) do {                                              \
        const char* src_ = Bp + (size_t)(t) * 16384;                      \
        _Pragma("unroll") for (int c_ = 0; c_ < 4; c_++)                  \
            GLDS(src_ + tid * 16 + c_ * 4096, BSEC(buf) + tid * 16 + c_ * 4096); \
    } while (0)

    // prologue: stage tile 0 into buf 0
    STAGE_B(0, 0);
    if constexpr (AMODE == 0) {
        float4 a0 = *(const float4*)(ApF), a1 = *(const float4*)(ApF + 4);
        u16x8 o; o[0]=f2b(a0.x); o[1]=f2b(a0.y); o[2]=f2b(a0.z); o[3]=f2b(a0.w);
        o[4]=f2b(a1.x); o[5]=f2b(a1.y); o[6]=f2b(a1.z); o[7]=f2b(a1.w);
        *(u16x8*)(ASEC(0) + awz) = o;
    } else if constexpr (AMODE == 1) {
        u16x8 v = *(const u16x8*)(ApH);
        *(u16x8*)(ASEC(0) + awz) = v;
    } else {
        GLDS(ApT + tid * 16, ASEC(0) + tid * 16);
    }
    __syncthreads();

    for (int t = 0; t < NT; t++) {
        const int cur = t & 1, nxt = cur ^ 1;
        const bool more = (t + 1 < NT);
        float4 a0, a1; u16x8 av;
        if (more) {
            STAGE_B(nxt, t + 1);
            if constexpr (AMODE == 0) {
                a0 = *(const float4*)(ApF + (t + 1) * 32);
                a1 = *(const float4*)(ApF + (t + 1) * 32 + 4);
            } else if constexpr (AMODE == 1) {
                av = *(const u16x8*)(ApH + (t + 1) * 64);
            } else {
                GLDS(ApT + (size_t)(t + 1) * 4096 + tid * 16, ASEC(nxt) + tid * 16);
            }
        }
        bf16x8 wf[4], xf[4];
#pragma unroll
        for (int m = 0; m < 4; m++)
            wf[m] = *(const bf16x8*)(BSEC(cur) + swz(wv * 64 + m * 16 + fr, sec));
#pragma unroll
        for (int n = 0; n < 4; n++)
            xf[n] = *(const bf16x8*)(ASEC(cur) + swz(n * 16 + fr, sec));
#pragma unroll
        for (int m = 0; m < 4; m++)
#pragma unroll
            for (int n = 0; n < 4; n++)
                acc[m][n] = __builtin_amdgcn_mfma_f32_16x16x32_bf16(wf[m], xf[n], acc[m][n], 0, 0, 0);
        if (more) {
            if constexpr (AMODE == 0) {
                u16x8 o; o[0]=f2b(a0.x); o[1]=f2b(a0.y); o[2]=f2b(a0.z); o[3]=f2b(a0.w);
                o[4]=f2b(a1.x); o[5]=f2b(a1.y); o[6]=f2b(a1.z); o[7]=f2b(a1.w);
                *(u16x8*)(ASEC(nxt) + awz) = o;
            } else if constexpr (AMODE == 1) {
                *(u16x8*)(ASEC(nxt) + awz) = av;
            }
        }
        __syncthreads();
    }

    if constexpr (EPI == 0) {
#pragma unroll
        for (int n = 0; n < 4; n++) {
            long node = row0 + n * 16 + fr;
            if (node < M) {
#pragma unroll
                for (int m = 0; m < 4; m++)
                    *(f32x4*)(Cf + node * 512 + cb * 256 + wv * 64 + m * 16 + hi4) = acc[m][n];
            }
        }
    } else if constexpr (EPI == 1) {
#pragma unroll
        for (int n = 0; n < 4; n++) {
            int nodeloc = n * 16 + fr;
            long node = row0 + nodeloc;
#pragma unroll
            for (int m = 0; m < 4; m++) {
                int hc = cb * 256 + wv * 64 + m * 16 + hi4;
                f32x4 bv = *(const f32x4*)(bias + hc);
                f32x4 v = acc[m][n] + bv;
                if (node < M) *(f32x4*)(Cf + node * 512 + hc) = v;
                ushort4 o; o.x = f2b(v[0]); o.y = f2b(v[1]); o.z = f2b(v[2]); o.w = f2b(v[3]);
                int tt = hc >> 5, ss = (hc & 31) >> 3, e = hc & 7;
                *(ushort4*)(hbpre + (size_t)blockIdx.x * 65536 + (size_t)tt * 4096 +
                            swz(nodeloc, ss) + e * 2) = o;
            }
        }
    } else {
        float* aS = (float*)smem;          // A/B buffers dead after last barrier
        if (tid < 64) aS[tid] = 0.f;
        __syncthreads();
#pragma unroll
        for (int n = 0; n < 4; n++) {
            float s = 0.f;
#pragma unroll
            for (int m = 0; m < 4; m++) {
                int gc = cb * 256 + wv * 64 + m * 16 + hi4;
                f32x4 bgv = *(const f32x4*)(bias + gc);
                f32x4 wav = *(const f32x4*)(Wa + gc);
#pragma unroll
                for (int r = 0; r < 4; r++)
                    s += tanhf(acc[m][n][r] + bgv[r]) * wav[r];
            }
            atomicAdd(&aS[n * 16 + fr], s);
        }
        __syncthreads();
        if (tid < 64) {
            long node = row0 + tid;
            if (node < M) atomicAdd(&alphaOut[node], aS[tid]);
        }
    }
#undef ASEC
#undef BSEC
#undef STAGE_B
}

// ---------- softmax over 20000 scalars (ba cancels) ----------
__global__ __launch_bounds__(1024) void softmax_kernel(const float* __restrict__ alpha,
                                                       float* __restrict__ att, int N) {
    __shared__ float red[16];
    __shared__ float bc[2];
    int tid = threadIdx.x, lane = tid & 63, wv = tid >> 6;
    float m = -3.4e38f;
    for (int i = tid; i < N; i += 1024) m = fmaxf(m, alpha[i]);
#pragma unroll
    for (int o = 32; o > 0; o >>= 1) m = fmaxf(m, __shfl_xor(m, o, 64));
    if (lane == 0) red[wv] = m;
    __syncthreads();
    if (tid == 0) {
        float mm = red[0];
        for (int i = 1; i < 16; i++) mm = fmaxf(mm, red[i]);
        bc[0] = mm;
    }
    __syncthreads();
    float Mx = bc[0];
    float s = 0.f;
    for (int i = tid; i < N; i += 1024) s += expf(alpha[i] - Mx);
#pragma unroll
    for (int o = 32; o > 0; o >>= 1) s += __shfl_xor(s, o, 64);
    if (lane == 0) red[wv] = s;
    __syncthreads();
    if (tid == 0) {
        float ss = 0.f;
        for (int i = 0; i < 16; i++) ss += red[i];
        bc[1] = ss;
    }
    __syncthreads();
    float inv = 1.f / bc[1];
    for (int i = tid; i < N; i += 1024) att[i] = expf(alpha[i] - Mx) * inv;
}

// ---------- launch ----------
extern "C" void kernel_launch(void* const* d_in, const int* in_sizes, int n_in,
                              void* d_out, int out_size, void* d_ws, size_t ws_size,
                              hipStream_t stream) {
    const float* x  = (const float*)d_in[0];
    const int*   ei = (const int*)d_in[1];     // [2][160000]: src then dst
    const float* W1 = (const float*)d_in[2];
    const float* b1 = (const float*)d_in[3];
    const float* W2 = (const float*)d_in[4];
    const float* b2 = (const float*)d_in[5];
    const float* Wg = (const float*)d_in[6];
    const float* bg = (const float*)d_in[7];
    const float* Wa = (const float*)d_in[8];
    // d_in[9] = ba: cancels in softmax, unused.

    const int M = 20000, IN = 2048, H = 512, E = 160000;

    char* ws = (char*)d_ws;
    float* y      = (float*)ws;                 // 40,960,000
    char*  W1p    = ws + 40960000;              //  2,097,152
    char*  W2p    = ws + 43057152;              //    524,288
    char*  Wgp    = ws + 43581440;              //    524,288
    unsigned short* h1b = (unsigned short*)(ws + 44105728);  // 20,480,000
    char*  hbpre  = ws + 64585728;              // 20,512,768 (313*65536)
    float* alpha  = (float*)(ws + 85098496);    //     80,000
    int*   counts = (int*)(ws + 85178496);      //     80,000
    int*   offs   = (int*)(ws + 85258496);      //     80,004
    int*   cursor = (int*)(ws + 85338504);      //     80,000
    int*   eids   = (int*)(ws + 85418504);      //    640,000

    float* hout = (float*)d_out;                 // [20000][512] f32
    float* att  = hout + (size_t)M * H;          // [20000] f32

    // weights -> pre-tiled + pre-swizzled images (bf16)
    convw_pre_kernel<<<4096, 256, 0, stream>>>(W1, W1p, IN);
    convw_pre_kernel<<<1024, 256, 0, stream>>>(W2, W2p, H);
    convw_pre_kernel<<<1024, 256, 0, stream>>>(Wg, Wgp, H);

    // CSR build by dst
    hipMemsetAsync(counts, 0, M * 4, stream);
    count_kernel<<<(E + 255) / 256, 256, 0, stream>>>(ei + E, counts, E);
    scan_kernel<<<1, 1024, 0, stream>>>(counts, offs, M);
    hipMemsetAsync(cursor, 0, M * 4, stream);
    bucket_kernel<<<(E + 255) / 256, 256, 0, stream>>>(ei, ei + E, offs, cursor, eids, E);

    // y = x @ W1
    gemm_sec<2048, 0, 0><<<dim3(313, 2), 256, 0, stream>>>(x, W1p, nullptr, y, nullptr, nullptr, nullptr, M);

    // h1 = bf16(relu(y_self + gather(y) + b1))
    gather_h1_kernel<<<10000, 256, 0, stream>>>(y, offs, eids, b1, h1b, M);

    // h = h1@W2+b2 -> hout (f32) + hbpre (bf16, pre-tiled+swizzled)
    gemm_sec<512, 1, 1><<<dim3(313, 2), 256, 0, stream>>>(h1b, W2p, b2, hout, hbpre, nullptr, nullptr, M);

    // alpha = rowsum(tanh(h@Wg+bg)*Wa), split over 2 col-blocks via atomics
    hipMemsetAsync(alpha, 0, M * 4, stream);
    gemm_sec<512, 2, 2><<<dim3(313, 2), 256, 0, stream>>>(hbpre, Wgp, bg, nullptr, nullptr, Wa, alpha, M);

    // att = softmax(alpha)
    softmax_kernel<<<1, 1024, 0, stream>>>(alpha, att, M);
}